// Round 8
// baseline (293.672 us; speedup 1.0000x reference)
//
#include <hip/hip_runtime.h>

#define HW_DIM 4096
#define NHW 64            // hw positions per block
#define NT 1024           // threads: 64 hw x 16 d-pairs
#define NCHUNK (HW_DIM / NHW)   // 64
#define V_F4 (NHW * 72)         // 4608 float4 = 73,728 B
#define SMEM_BYTES (V_F4 * 16 + NHW * 81 * 4)   // 73,728 + 20,736 = 94,464 B

// v tile: [64][72 float4] XOR-swizzled in f4 units (q ^ (hwl&7)) — aligned
//   ds_write_b128 staging, float2 compute reads at +j*128B immediates.
// lp: [64][81] packed logits, staged f4-coalesced; softmax in-place.
// Wave = 64 lanes = 64 consecutive hw, one d-group -> every global store is a
//   single 256B contiguous segment (2x round-6's 128B): the write-efficiency lever.
// T14 split: v global->regs issued first; softmax hides the latency; regs->LDS after.

__global__ __launch_bounds__(NT)
void attn9_kernel(const float* __restrict__ logits,
                  const float* __restrict__ v,
                  float* __restrict__ out)
{
    extern __shared__ char smem[];
    float4* vs4 = reinterpret_cast<float4*>(smem);
    float*  lp  = reinterpret_cast<float*>(smem + V_F4 * 16);

    const int t = threadIdx.x;
    const int bid = blockIdx.x;
    const int chunk = bid & (NCHUNK - 1);   // 0..63
    const int bh = bid >> 6;                // b*8 + h, 0..31
    const int hw0 = bh * HW_DIM + chunk * NHW;

    // ---- 1. issue v global loads -> registers (held across softmax) ----
    const float4* vg = reinterpret_cast<const float4*>(v + (size_t)hw0 * 288);
    float4 vr0 = vg[t];
    float4 vr1 = vg[t + NT];
    float4 vr2 = vg[t + 2 * NT];
    float4 vr3 = vg[t + 3 * NT];
    float4 vr4 = {0.f, 0.f, 0.f, 0.f};
    if (t < V_F4 - 4 * NT) vr4 = vg[t + 4 * NT];    // t < 512

    // ---- 2. stage logits: coalesced f4 -> LDS ----
    {
        const float4* lg4 = reinterpret_cast<const float4*>(logits + (size_t)hw0 * 81);
        float4* lp4 = reinterpret_cast<float4*>(lp);
        lp4[t] = lg4[t];                              // 0..1023
        if (t < NHW * 81 / 4 - NT) lp4[t + NT] = lg4[t + NT];   // t < 272
    }
    __syncthreads();

    // ---- 3. softmax in-place (t < 576); idle waves fall through to v ds_writes ----
    if (t < NHW * 9) {
        const int hwl = t / 9;
        const int i = t - hwl * 9;
        float* row = &lp[hwl * 81 + i * 9];
        float x[9];
        #pragma unroll
        for (int j = 0; j < 9; ++j) x[j] = row[j] * 0.17677669529663687f;
        float m = x[0];
        #pragma unroll
        for (int j = 1; j < 9; ++j) m = fmaxf(m, x[j]);
        float e[9];
        float s = 0.f;
        #pragma unroll
        for (int j = 0; j < 9; ++j) { e[j] = expf(x[j] - m); s += e[j]; }
        const float inv = 1.0f / (s + 1e-12f);
        #pragma unroll
        for (int j = 0; j < 9; ++j) row[j] = e[j] * inv;
    }

    // ---- 4. v regs -> LDS (swizzled, aligned f4 writes) ----
    {
        #pragma unroll
        for (int k = 0; k < 5; ++k) {
            int idx4 = t + k * NT;
            if (k < 4 || t < V_F4 - 4 * NT) {
                int hwl = idx4 / 72;
                int q   = idx4 - hwl * 72;
                float4 val = (k == 0) ? vr0 : (k == 1) ? vr1 : (k == 2) ? vr2
                           : (k == 3) ? vr3 : vr4;
                vs4[hwl * 72 + (q ^ (hwl & 7))] = val;
            }
        }
    }
    __syncthreads();

    // ---- 5. compute: thread (hw 0..63, dg 0..15); 256B-contiguous wave stores ----
    const int hw = t & (NHW - 1);
    const int dg = t >> 6;
    const int d0 = dg * 2;

    const char* vbase = reinterpret_cast<const char*>(vs4)
        + (size_t)hw * 1152                      // 72 f4 * 16B per hw row
        + (((d0 >> 2) ^ (hw & 7)) << 4)          // swizzled f4 unit
        + ((d0 & 3) << 2);                       // 0 or 8 bytes
    float va[9], vb[9];
    #pragma unroll
    for (int j = 0; j < 9; ++j) {
        float2 vv = *reinterpret_cast<const float2*>(vbase + j * 128);
        va[j] = vv.x; vb[j] = vv.y;
    }

    float* ob = out + (size_t)bh * 288 * HW_DIM + chunk * NHW + hw;
    const float* prow = &lp[hw * 81];
    #pragma unroll
    for (int i = 0; i < 9; ++i) {
        float a0 = 0.f, a1 = 0.f;
        #pragma unroll
        for (int j = 0; j < 9; ++j) {
            float p = prow[i * 9 + j];
            a0 = fmaf(p, va[j], a0);
            a1 = fmaf(p, vb[j], a1);
        }
        ob[(size_t)(d0 * 9 + i) * HW_DIM]       = a0;
        ob[(size_t)((d0 + 1) * 9 + i) * HW_DIM] = a1;
    }
}

extern "C" void kernel_launch(void* const* d_in, const int* in_sizes, int n_in,
                              void* d_out, int out_size, void* d_ws, size_t ws_size,
                              hipStream_t stream) {
    const float* logits = (const float*)d_in[0];
    const float* v      = (const float*)d_in[1];
    float* out          = (float*)d_out;
    hipFuncSetAttribute(reinterpret_cast<const void*>(attn9_kernel),
                        hipFuncAttributeMaxDynamicSharedMemorySize, SMEM_BYTES);
    const int grid = 4 * 8 * NCHUNK;   // 2048 blocks
    attn9_kernel<<<grid, NT, SMEM_BYTES, stream>>>(logits, v, out);
}